// Round 12
// baseline (185.470 us; speedup 1.0000x reference)
//
#include <hip/hip_runtime.h>
#include <hip/hip_fp16.h>
#include <stdint.h>

typedef uint32_t u32;
typedef float    f32x4 __attribute__((ext_vector_type(4)));
typedef int      i32x4 __attribute__((ext_vector_type(4)));
typedef uint32_t u32x4 __attribute__((ext_vector_type(4)));

#define GRID_BLOCKS 768
#define BS 256
#define GT (GRID_BLOCKS * BS)   // 196608 threads
#define SUBW 96                 // blocks per sub-counter (768/8)

// ---- relaxed agent-scope helpers (L3-coherent, no cache-maintenance) ------
__device__ __forceinline__ u32 aload(const u32* p) {
  return __hip_atomic_load(p, __ATOMIC_RELAXED, __HIP_MEMORY_SCOPE_AGENT);
}
__device__ __forceinline__ void astore(u32* p, u32 v) {
  __hip_atomic_store(p, v, __ATOMIC_RELAXED, __HIP_MEMORY_SCOPE_AGENT);
}
__device__ __forceinline__ u32 armw_add(u32* p, u32 v) {
  return __hip_atomic_fetch_add(p, v, __ATOMIC_RELAXED, __HIP_MEMORY_SCOPE_AGENT);
}

// ---------------------------------------------------------------------------
// threefry2x32 (JAX): bit-exact.
// ---------------------------------------------------------------------------
struct U2 { u32 a, b; };

__host__ __device__ inline U2 tf2x32(u32 k0, u32 k1, u32 x0, u32 x1) {
  u32 k2 = k0 ^ k1 ^ 0x1BD11BDAu;
#define TFR(r) { x0 += x1; x1 = (x1 << (r)) | (x1 >> (32 - (r))); x1 ^= x0; }
  x0 += k0; x1 += k1;
  TFR(13) TFR(15) TFR(26) TFR(6)  x0 += k1; x1 += k2 + 1u;
  TFR(17) TFR(29) TFR(16) TFR(24) x0 += k2; x1 += k0 + 2u;
  TFR(13) TFR(15) TFR(26) TFR(6)  x0 += k0; x1 += k1 + 3u;
  TFR(17) TFR(29) TFR(16) TFR(24) x0 += k1; x1 += k2 + 4u;
  TFR(13) TFR(15) TFR(26) TFR(6)  x0 += k2; x1 += k0 + 5u;
#undef TFR
  return {x0, x1};
}

__device__ __forceinline__ u32 rbits(u32 k0, u32 k1, u32 j) {
  U2 r = tf2x32(k0, k1, 0u, j);
  return r.a ^ r.b;
}

__device__ __forceinline__ float bits_to_u01(u32 bits) {
  return __uint_as_float(0x3F800000u | (bits >> 9)) - 1.0f;
}

__device__ __forceinline__ float bits_to_upm1(u32 bits) {
  const float LO = -0.99999994f;
  float f = bits_to_u01(bits);
  return fmaxf(LO, f * 2.0f + LO);
}

__device__ __forceinline__ float erfinv32(float x) {
  float w = -__logf((1.0f - x) * (1.0f + x));
  float p;
  if (w < 5.0f) {
    w -= 2.5f;
    p = 2.81022636e-08f;
    p = fmaf(p, w, 3.43273939e-07f);
    p = fmaf(p, w, -3.5233877e-06f);
    p = fmaf(p, w, -4.39150654e-06f);
    p = fmaf(p, w, 0.00021858087f);
    p = fmaf(p, w, -0.00125372503f);
    p = fmaf(p, w, -0.00417768164f);
    p = fmaf(p, w, 0.246640727f);
    p = fmaf(p, w, 1.50140941f);
  } else {
    w = sqrtf(w) - 3.0f;
    p = -0.000200214257f;
    p = fmaf(p, w, 0.000100950558f);
    p = fmaf(p, w, 0.00134934322f);
    p = fmaf(p, w, -0.00367342844f);
    p = fmaf(p, w, 0.00573950773f);
    p = fmaf(p, w, -0.0076224613f);
    p = fmaf(p, w, 0.00943887047f);
    p = fmaf(p, w, 1.00167406f);
    p = fmaf(p, w, 2.83297682f);
  }
  return p * x;
}

__device__ __forceinline__ float normal_from_bits(u32 bits) {
  return 1.41421356f * erfinv32(bits_to_upm1(bits));
}

__device__ __forceinline__ float softplusf(float x) {
  return fmaxf(x, 0.0f) + __logf(1.0f + __expf(-fabsf(x)));
}

__device__ __forceinline__ float kl_term(float mu, float sp) {
  return fmaf(0.5f, fmaf(sp, sp, mu * mu), -__logf(sp) - 0.5f);
}

union H16 {
  u32 w[8];
  __half h[16];
};

// ---------------------------------------------------------------------------
// Grid barrier: hierarchical arrival (8 padded sub-counters -> master -> gen),
// RELAXED RMW atomics only (no compiler fences / no buffer_wbl2 storm).
// Data coherence comes from sc1 (agent-scope) data ops + vmcnt(0) here.
// Poll: plain agent atomic load + s_sleep; RMW re-check every 64 polls as a
// staleness safety net; bounded spin -> clean wrong-answer, never a hang.
// Layout (u32 idx in ws): sub[i]@i*16 (i<8), master@128, gen@144.
// ---------------------------------------------------------------------------
__device__ __forceinline__ void grid_barrier(u32* bs) {
  __syncthreads();
  if (threadIdx.x == 0) {
    asm volatile("s_waitcnt vmcnt(0)" ::: "memory");
    u32* gen = bs + 144;
    u32 g = armw_add(gen, 0u);                       // coherent read of gen
    u32* sub = bs + (blockIdx.x & 7) * 16;
    u32 s = armw_add(sub, 1u);
    if (s == SUBW - 1) {                             // last of this sub-group
      astore(sub, 0u);
      u32 m = armw_add(bs + 128, 1u);
      if (m == 7u) {                                 // last sub-group overall
        astore(bs + 128, 0u);
        armw_add(gen, 1u);                           // release: flip generation
      }
    }
    u32 it = 0;
    for (;;) {
      u32 cur = ((it & 63u) == 63u) ? armw_add(gen, 0u) : aload(gen);
      if (cur != g) break;
      __builtin_amdgcn_s_sleep(16);
      if (++it > 2000000u) break;                    // hang guard (~1.7s max)
    }
  }
  __syncthreads();
}

// ---------------------------------------------------------------------------
struct Params {
  const float* x0;
  const int *ii1, *ii2, *ii3, *ii4, *ii5;
  const float *mu1, *mu2, *mu3, *mu4, *mu5;
  const float *rho1, *rho2, *rho3, *rho4, *rho5;
  const float *g1, *g2, *g3, *g4;
  const float *b1, *b2, *b3, *b4;
  u32 *hu1, *hu2, *hu3, *hu4;   // f16 intermediates viewed as u32 words
  float* out;
  u32* bar;        // barrier state (u32[160], zeroed per call)
  u32* klp;        // [GRID_BLOCKS] float-bits partials
  u32 K[10][2];
};

// ---------------------------------------------------------------------------
// Stage 1: x0 batch-major f32 [16,512] -> h1 [2048 nodes x 16] (sc1 stores)
// ---------------------------------------------------------------------------
__device__ __forceinline__ float first_body(
    int f, const float* __restrict__ xin,
    const int* __restrict__ ii, const float* __restrict__ mu,
    const float* __restrict__ rho, const float* __restrict__ gg,
    const float* __restrict__ bbp, u32* hu_out,
    u32 kw0, u32 kw1, u32 kd0, u32 kd1)
{
  const int nc = 512, nf = 2048;
  i32x4 iv = __builtin_nontemporal_load(reinterpret_cast<const i32x4*>(ii) + f);
  f32x4 m4 = __builtin_nontemporal_load(reinterpret_cast<const f32x4*>(mu) + f);
  f32x4 r4 = __builtin_nontemporal_load(reinterpret_cast<const f32x4*>(rho) + f);

  float w[4];
  float kl = 0.0f;
#pragma unroll
  for (int d = 0; d < 4; ++d) {
    u32 e = 4u * (u32)f + (u32)d;
    float sp  = softplusf(r4[d]);
    float eps = normal_from_bits(rbits(kw0, kw1, e));
    w[d] = fmaf(sp, eps, m4[d]);
    kl += kl_term(m4[d], sp);
  }

  float y[16];
#pragma unroll
  for (int b = 0; b < 16; ++b) {
    float s = 0.0f;
#pragma unroll
    for (int d = 0; d < 4; ++d) s = fmaf(xin[b * nc + iv[d]], w[d], s);
    y[b] = s;
  }

  float m = 0.0f;
#pragma unroll
  for (int b = 0; b < 16; ++b) m += y[b];
  m *= 0.0625f;
  float v = 0.0f;
#pragma unroll
  for (int b = 0; b < 16; ++b) { float dd = y[b] - m; v = fmaf(dd, dd, v); }
  v *= 0.0625f;
  float sc = rsqrtf(v + 1e-5f) * gg[f];
  float bi = bbp[f];

  H16 o;
#pragma unroll
  for (int b = 0; b < 16; ++b) {
    float u = bits_to_u01(rbits(kd0, kd1, (u32)b * (u32)nf + (u32)f));
    float h = fmaxf(fmaf(y[b] - m, sc, bi), 0.0f);
    o.h[b] = __float2half_rn((u < 0.9f) ? h * (1.0f / 0.9f) : 0.0f);
  }
  u32* op = hu_out + (size_t)f * 8;
#pragma unroll
  for (int j = 0; j < 8; ++j) astore(op + j, o.w[j]);
  return kl;
}

// ---------------------------------------------------------------------------
// Stages 2-4: h[nc] -> h[nf]; sc1 gathers + sc1 stores
// ---------------------------------------------------------------------------
__device__ __forceinline__ float mid_body(
    int f, int nf, u32* hu_in,
    const int* __restrict__ ii, const float* __restrict__ mu,
    const float* __restrict__ rho, const float* __restrict__ gg,
    const float* __restrict__ bbp, u32* hu_out,
    u32 kw0, u32 kw1, u32 kd0, u32 kd1)
{
  i32x4 iv = __builtin_nontemporal_load(reinterpret_cast<const i32x4*>(ii) + f);

  H16 xg[4];
#pragma unroll
  for (int d = 0; d < 4; ++d) {
    u32* xp = hu_in + (size_t)iv[d] * 8;
#pragma unroll
    for (int j = 0; j < 8; ++j) xg[d].w[j] = aload(xp + j);
  }

  f32x4 m4 = __builtin_nontemporal_load(reinterpret_cast<const f32x4*>(mu) + f);
  f32x4 r4 = __builtin_nontemporal_load(reinterpret_cast<const f32x4*>(rho) + f);

  float w[4];
  float kl = 0.0f;
#pragma unroll
  for (int d = 0; d < 4; ++d) {
    u32 e = 4u * (u32)f + (u32)d;
    float sp  = softplusf(r4[d]);
    float eps = normal_from_bits(rbits(kw0, kw1, e));
    w[d] = fmaf(sp, eps, m4[d]);
    kl += kl_term(m4[d], sp);
  }

  float y[16];
#pragma unroll
  for (int b = 0; b < 16; ++b) y[b] = 0.0f;
#pragma unroll
  for (int d = 0; d < 4; ++d)
#pragma unroll
    for (int b = 0; b < 16; ++b)
      y[b] = fmaf(__half2float(xg[d].h[b]), w[d], y[b]);

  float m = 0.0f;
#pragma unroll
  for (int b = 0; b < 16; ++b) m += y[b];
  m *= 0.0625f;
  float v = 0.0f;
#pragma unroll
  for (int b = 0; b < 16; ++b) { float dd = y[b] - m; v = fmaf(dd, dd, v); }
  v *= 0.0625f;
  float sc = rsqrtf(v + 1e-5f) * gg[f];
  float bi = bbp[f];

  H16 o;
#pragma unroll
  for (int b = 0; b < 16; ++b) {
    float u = bits_to_u01(rbits(kd0, kd1, (u32)b * (u32)nf + (u32)f));
    float h = fmaxf(fmaf(y[b] - m, sc, bi), 0.0f);
    o.h[b] = __float2half_rn((u < 0.9f) ? h * (1.0f / 0.9f) : 0.0f);
  }
  u32* op = hu_out + (size_t)f * 8;
#pragma unroll
  for (int j = 0; j < 8; ++j) astore(op + j, o.w[j]);
  return kl;
}

// ---------------------------------------------------------------------------
// Stage 5: h4 -> f32 out [16, 524288, 3] (NT stores; sc1 gathers)
// ---------------------------------------------------------------------------
__device__ __forceinline__ float final_body(
    int f, u32* hu_in, const int* __restrict__ ii,
    const float* __restrict__ mu, const float* __restrict__ rho,
    float* __restrict__ out, u32 kw0, u32 kw1)
{
  const int nf = 524288;
  i32x4 iv = __builtin_nontemporal_load(reinterpret_cast<const i32x4*>(ii) + f);

  H16 xg[4];
#pragma unroll
  for (int d = 0; d < 4; ++d) {
    u32* xp = hu_in + (size_t)iv[d] * 8;
#pragma unroll
    for (int j = 0; j < 8; ++j) xg[d].w[j] = aload(xp + j);
  }

  const f32x4* mp = reinterpret_cast<const f32x4*>(mu) + (size_t)f * 3;
  const f32x4* rp = reinterpret_cast<const f32x4*>(rho) + (size_t)f * 3;
  float w[4][3];
  float kl = 0.0f;
#pragma unroll
  for (int h = 0; h < 3; ++h) {
    f32x4 m4 = __builtin_nontemporal_load(mp + h);
    f32x4 r4 = __builtin_nontemporal_load(rp + h);
#pragma unroll
    for (int k = 0; k < 4; ++k) {
      int t = 4 * h + k;                 // flat weight index 0..11 = 3*d+o
      u32 j = 12u * (u32)f + (u32)t;
      float sp  = softplusf(r4[k]);
      float eps = normal_from_bits(rbits(kw0, kw1, j));
      w[t / 3][t % 3] = fmaf(sp, eps, m4[k]);
      kl += kl_term(m4[k], sp);
    }
  }

#pragma unroll
  for (int q = 0; q < 4; ++q) {
    float acc[4][3];
#pragma unroll
    for (int k = 0; k < 4; ++k)
#pragma unroll
      for (int o = 0; o < 3; ++o) acc[k][o] = 0.0f;

#pragma unroll
    for (int d = 0; d < 4; ++d)
#pragma unroll
      for (int k = 0; k < 4; ++k) {
        float xv = __half2float(xg[d].h[4 * q + k]);
#pragma unroll
        for (int o = 0; o < 3; ++o)
          acc[k][o] = fmaf(xv, w[d][o], acc[k][o]);
      }

#pragma unroll
    for (int k = 0; k < 4; ++k) {
      size_t base = ((size_t)(4 * q + k) * nf + (size_t)f) * 3;
      __builtin_nontemporal_store(acc[k][0], out + base + 0);
      __builtin_nontemporal_store(acc[k][1], out + base + 1);
      __builtin_nontemporal_store(acc[k][2], out + base + 2);
    }
  }
  return kl;
}

// ---------------------------------------------------------------------------
// Single-dispatch fused pipeline. 768 blocks x 256 @ launch_bounds(256,4):
// capacity 4 blocks/CU x 256 CU = 1024 >= 768 -> all co-resident (round-8
// occupancy 36% confirms).
// ---------------------------------------------------------------------------
__global__ __launch_bounds__(256, 4) void fused_all(Params p) {
  const int tid = threadIdx.x;
  const int gid = blockIdx.x * BS + tid;

  float kl = 0.0f;

  if (gid < 2048)
    kl += first_body(gid, p.x0, p.ii1, p.mu1, p.rho1, p.g1, p.b1, p.hu1,
                     p.K[0][0], p.K[0][1], p.K[1][0], p.K[1][1]);
  grid_barrier(p.bar);

  if (gid < 8192)
    kl += mid_body(gid, 8192, p.hu1, p.ii2, p.mu2, p.rho2, p.g2, p.b2, p.hu2,
                   p.K[2][0], p.K[2][1], p.K[3][0], p.K[3][1]);
  grid_barrier(p.bar);

  if (gid < 32768)
    kl += mid_body(gid, 32768, p.hu2, p.ii3, p.mu3, p.rho3, p.g3, p.b3, p.hu3,
                   p.K[4][0], p.K[4][1], p.K[5][0], p.K[5][1]);
  grid_barrier(p.bar);

  if (gid < 131072)
    kl += mid_body(gid, 131072, p.hu3, p.ii4, p.mu4, p.rho4, p.g4, p.b4, p.hu4,
                   p.K[6][0], p.K[6][1], p.K[7][0], p.K[7][1]);
  grid_barrier(p.bar);

  for (int n = gid; n < 524288; n += GT)
    kl += final_body(n, p.hu4, p.ii5, p.mu5, p.rho5, p.out, p.K[8][0], p.K[8][1]);

  // block KL partial -> klp (sc1 store), then barrier, block 0 reduces.
  __shared__ float sm[256];
  sm[tid] = kl;
  __syncthreads();
  for (int off = 128; off > 0; off >>= 1) {
    if (tid < off) sm[tid] += sm[tid + off];
    __syncthreads();
  }
  if (tid == 0) astore(p.klp + blockIdx.x, __float_as_uint(sm[0]));

  grid_barrier(p.bar);

  if (blockIdx.x == 0) {
    float s = 0.0f;
#pragma unroll
    for (int i = 0; i < 3; ++i)                       // 768 = 3 * 256
      s += __uint_as_float(aload(p.klp + i * 256 + tid));
    __shared__ float sm2[256];
    sm2[tid] = s;
    __syncthreads();
    for (int off = 128; off > 0; off >>= 1) {
      if (tid < off) sm2[tid] += sm2[tid + off];
      __syncthreads();
    }
    if (tid == 0) p.out[(size_t)16 * 524288 * 3] = sm2[0];
  }
}

// ---------------------------------------------------------------------------
extern "C" void kernel_launch(void* const* d_in, const int* in_sizes, int n_in,
                              void* d_out, int out_size, void* d_ws, size_t ws_size,
                              hipStream_t stream) {
  Params p;
  p.x0   = (const float*)d_in[0];
  p.ii1  = (const int*)d_in[2];
  p.mu1  = (const float*)d_in[3];
  p.rho1 = (const float*)d_in[4];
  p.g1   = (const float*)d_in[5];
  p.b1   = (const float*)d_in[6];
  p.ii2  = (const int*)d_in[8];
  p.mu2  = (const float*)d_in[9];
  p.rho2 = (const float*)d_in[10];
  p.g2   = (const float*)d_in[11];
  p.b2   = (const float*)d_in[12];
  p.ii3  = (const int*)d_in[14];
  p.mu3  = (const float*)d_in[15];
  p.rho3 = (const float*)d_in[16];
  p.g3   = (const float*)d_in[17];
  p.b3   = (const float*)d_in[18];
  p.ii4  = (const int*)d_in[20];
  p.mu4  = (const float*)d_in[21];
  p.rho4 = (const float*)d_in[22];
  p.g4   = (const float*)d_in[23];
  p.b4   = (const float*)d_in[24];
  p.ii5  = (const int*)d_in[26];
  p.mu5  = (const float*)d_in[27];
  p.rho5 = (const float*)d_in[28];

  u32* wsu = (u32*)d_ws;
  p.out = (float*)d_out;
  p.bar = wsu;                             // u32[160]: sub@i*16, master@128, gen@144
  p.klp = wsu + 256;                       // [768]
  p.hu1 = wsu + 1024;                      // 2048 *8 u32
  p.hu2 = p.hu1 + 2048  * 8;               // 8192 *8
  p.hu3 = p.hu2 + 8192  * 8;               // 32768*8
  p.hu4 = p.hu3 + 32768 * 8;               // 131072*8

  for (u32 i = 0; i < 10; ++i) {
    U2 r = tf2x32(0u, 42u, 0u, i);
    p.K[i][0] = r.a; p.K[i][1] = r.b;
  }

  // zero barrier state every call (graph-capturable async memset; the
  // dispatch boundary writes it back to the coherence point before fused_all)
  hipMemsetAsync(d_ws, 0, 1024, stream);

  fused_all<<<dim3(GRID_BLOCKS), dim3(BS), 0, stream>>>(p);
}

// Round 13
// 179.172 us; speedup vs baseline: 1.0351x; 1.0351x over previous
//
#include <hip/hip_runtime.h>
#include <hip/hip_fp16.h>
#include <stdint.h>

typedef uint32_t u32;
typedef unsigned long long u64;
typedef float    f32x4 __attribute__((ext_vector_type(4)));
typedef int      i32x4 __attribute__((ext_vector_type(4)));

#define GRID_BLOCKS 1024
#define BS 256
#define GT (GRID_BLOCKS * BS)   // 262144 threads
#define SUBW 64                 // blocks per sub-counter (1024/16)

// ---- relaxed agent-scope helpers ------------------------------------------
// RMWs execute at the L3 coherence point (always fresh). Relaxed atomic LOADS
// can hit a stale per-XCD L2 copy (measured r12: poll loads never saw the gen
// flip; only RMW rechecks did) -> ALL cross-XCD polling must be RMW.
__device__ __forceinline__ void astore(u32* p, u32 v) {
  __hip_atomic_store(p, v, __ATOMIC_RELAXED, __HIP_MEMORY_SCOPE_AGENT);
}
__device__ __forceinline__ u32 aload1st(const u32* p) {   // first-touch loads only
  return __hip_atomic_load(p, __ATOMIC_RELAXED, __HIP_MEMORY_SCOPE_AGENT);
}
__device__ __forceinline__ u32 armw_add(u32* p, u32 v) {
  return __hip_atomic_fetch_add(p, v, __ATOMIC_RELAXED, __HIP_MEMORY_SCOPE_AGENT);
}
__device__ __forceinline__ u64 armw_add64(u64* p, u64 v) {
  return __hip_atomic_fetch_add(p, v, __ATOMIC_RELAXED, __HIP_MEMORY_SCOPE_AGENT);
}

// ---------------------------------------------------------------------------
// threefry2x32 (JAX): bit-exact.
// ---------------------------------------------------------------------------
struct U2 { u32 a, b; };

__host__ __device__ inline U2 tf2x32(u32 k0, u32 k1, u32 x0, u32 x1) {
  u32 k2 = k0 ^ k1 ^ 0x1BD11BDAu;
#define TFR(r) { x0 += x1; x1 = (x1 << (r)) | (x1 >> (32 - (r))); x1 ^= x0; }
  x0 += k0; x1 += k1;
  TFR(13) TFR(15) TFR(26) TFR(6)  x0 += k1; x1 += k2 + 1u;
  TFR(17) TFR(29) TFR(16) TFR(24) x0 += k2; x1 += k0 + 2u;
  TFR(13) TFR(15) TFR(26) TFR(6)  x0 += k0; x1 += k1 + 3u;
  TFR(17) TFR(29) TFR(16) TFR(24) x0 += k1; x1 += k2 + 4u;
  TFR(13) TFR(15) TFR(26) TFR(6)  x0 += k2; x1 += k0 + 5u;
#undef TFR
  return {x0, x1};
}

__device__ __forceinline__ u32 rbits(u32 k0, u32 k1, u32 j) {
  U2 r = tf2x32(k0, k1, 0u, j);
  return r.a ^ r.b;
}

__device__ __forceinline__ float bits_to_u01(u32 bits) {
  return __uint_as_float(0x3F800000u | (bits >> 9)) - 1.0f;
}

__device__ __forceinline__ float bits_to_upm1(u32 bits) {
  const float LO = -0.99999994f;
  float f = bits_to_u01(bits);
  return fmaxf(LO, f * 2.0f + LO);
}

__device__ __forceinline__ float erfinv32(float x) {
  float w = -__logf((1.0f - x) * (1.0f + x));
  float p;
  if (w < 5.0f) {
    w -= 2.5f;
    p = 2.81022636e-08f;
    p = fmaf(p, w, 3.43273939e-07f);
    p = fmaf(p, w, -3.5233877e-06f);
    p = fmaf(p, w, -4.39150654e-06f);
    p = fmaf(p, w, 0.00021858087f);
    p = fmaf(p, w, -0.00125372503f);
    p = fmaf(p, w, -0.00417768164f);
    p = fmaf(p, w, 0.246640727f);
    p = fmaf(p, w, 1.50140941f);
  } else {
    w = sqrtf(w) - 3.0f;
    p = -0.000200214257f;
    p = fmaf(p, w, 0.000100950558f);
    p = fmaf(p, w, 0.00134934322f);
    p = fmaf(p, w, -0.00367342844f);
    p = fmaf(p, w, 0.00573950773f);
    p = fmaf(p, w, -0.0076224613f);
    p = fmaf(p, w, 0.00943887047f);
    p = fmaf(p, w, 1.00167406f);
    p = fmaf(p, w, 2.83297682f);
  }
  return p * x;
}

__device__ __forceinline__ float normal_from_bits(u32 bits) {
  return 1.41421356f * erfinv32(bits_to_upm1(bits));
}

__device__ __forceinline__ float softplusf(float x) {
  return fmaxf(x, 0.0f) + __logf(1.0f + __expf(-fabsf(x)));
}

__device__ __forceinline__ float kl_term(float mu, float sp) {
  return fmaf(0.5f, fmaf(sp, sp, mu * mu), -__logf(sp) - 0.5f);
}

union H16 {
  u32 w[8];
  __half h[16];
};

// ---------------------------------------------------------------------------
// Grid barrier v3. ws layout (u32 idx): sub[i]@i*32 (i<16), master@512,
// mirror[j]@1024+j*32 (j<64), klsum(u64)@3072, klcnt@3104. Zeroed per call.
// Arrival: sub (64 blocks each) -> master -> flip all 64 mirrors to gen_next.
// Poll: RMW(+0) on own mirror (16 blocks/line) + s_sleep(16) (~0.43us period).
// Bounded spin -> clean wrong answer, never a hang.
// ---------------------------------------------------------------------------
__device__ __forceinline__ void grid_barrier(u32* bs, u32 gen_next) {
  __syncthreads();
  if (threadIdx.x == 0) {
    asm volatile("s_waitcnt vmcnt(0)" ::: "memory");   // data stores drained
    u32* sub = bs + (blockIdx.x & 15) * 32;
    u32 s = armw_add(sub, 1u);
    if (s == SUBW - 1) {                               // last in sub-group
      astore(sub, 0u);
      asm volatile("s_waitcnt vmcnt(0)" ::: "memory");
      u32 m = armw_add(bs + 512, 1u);
      if (m == 15u) {                                  // last overall
        astore(bs + 512, 0u);
        asm volatile("s_waitcnt vmcnt(0)" ::: "memory");
#pragma unroll
        for (int j = 0; j < 64; ++j) astore(bs + 1024 + j * 32, gen_next);
      }
    }
    u32* mir = bs + 1024 + (blockIdx.x & 63) * 32;
    u32 it = 0;
    while (armw_add(mir, 0u) < gen_next) {             // RMW poll: L3-fresh
      __builtin_amdgcn_s_sleep(16);
      if (++it > 3000000u) break;                      // hang guard
    }
  }
  __syncthreads();
}

// ---------------------------------------------------------------------------
struct Params {
  const float* x0;
  const int *ii1, *ii2, *ii3, *ii4, *ii5;
  const float *mu1, *mu2, *mu3, *mu4, *mu5;
  const float *rho1, *rho2, *rho3, *rho4, *rho5;
  const float *g1, *g2, *g3, *g4;
  const float *b1, *b2, *b3, *b4;
  u32 *hu1, *hu2, *hu3, *hu4;   // f16 intermediates viewed as u32 words
  float* out;
  u32* bar;        // barrier + KL state (zeroed per call)
  u32 K[10][2];
};

// ---------------------------------------------------------------------------
// Stage 1: x0 batch-major f32 [16,512] -> h1 [2048 nodes x 16]
// ---------------------------------------------------------------------------
__device__ __forceinline__ float first_body(
    int f, const float* __restrict__ xin,
    const int* __restrict__ ii, const float* __restrict__ mu,
    const float* __restrict__ rho, const float* __restrict__ gg,
    const float* __restrict__ bbp, u32* hu_out,
    u32 kw0, u32 kw1, u32 kd0, u32 kd1)
{
  const int nc = 512, nf = 2048;
  i32x4 iv = __builtin_nontemporal_load(reinterpret_cast<const i32x4*>(ii) + f);
  f32x4 m4 = __builtin_nontemporal_load(reinterpret_cast<const f32x4*>(mu) + f);
  f32x4 r4 = __builtin_nontemporal_load(reinterpret_cast<const f32x4*>(rho) + f);

  float w[4];
  float kl = 0.0f;
#pragma unroll
  for (int d = 0; d < 4; ++d) {
    u32 e = 4u * (u32)f + (u32)d;
    float sp  = softplusf(r4[d]);
    float eps = normal_from_bits(rbits(kw0, kw1, e));
    w[d] = fmaf(sp, eps, m4[d]);
    kl += kl_term(m4[d], sp);
  }

  float y[16];
#pragma unroll
  for (int b = 0; b < 16; ++b) {
    float s = 0.0f;
#pragma unroll
    for (int d = 0; d < 4; ++d) s = fmaf(xin[b * nc + iv[d]], w[d], s);
    y[b] = s;
  }

  float m = 0.0f;
#pragma unroll
  for (int b = 0; b < 16; ++b) m += y[b];
  m *= 0.0625f;
  float v = 0.0f;
#pragma unroll
  for (int b = 0; b < 16; ++b) { float dd = y[b] - m; v = fmaf(dd, dd, v); }
  v *= 0.0625f;
  float sc = rsqrtf(v + 1e-5f) * gg[f];
  float bi = bbp[f];

  H16 o;
#pragma unroll
  for (int b = 0; b < 16; ++b) {
    float u = bits_to_u01(rbits(kd0, kd1, (u32)b * (u32)nf + (u32)f));
    float h = fmaxf(fmaf(y[b] - m, sc, bi), 0.0f);
    o.h[b] = __float2half_rn((u < 0.9f) ? h * (1.0f / 0.9f) : 0.0f);
  }
  u32* op = hu_out + (size_t)f * 8;
#pragma unroll
  for (int j = 0; j < 8; ++j) astore(op + j, o.w[j]);
  return kl;
}

// ---------------------------------------------------------------------------
// Stages 2-4: h[nc] -> h[nf]
// ---------------------------------------------------------------------------
__device__ __forceinline__ float mid_body(
    int f, int nf, u32* hu_in,
    const int* __restrict__ ii, const float* __restrict__ mu,
    const float* __restrict__ rho, const float* __restrict__ gg,
    const float* __restrict__ bbp, u32* hu_out,
    u32 kw0, u32 kw1, u32 kd0, u32 kd1)
{
  i32x4 iv = __builtin_nontemporal_load(reinterpret_cast<const i32x4*>(ii) + f);

  H16 xg[4];
#pragma unroll
  for (int d = 0; d < 4; ++d) {
    u32* xp = hu_in + (size_t)iv[d] * 8;
#pragma unroll
    for (int j = 0; j < 8; ++j) xg[d].w[j] = aload1st(xp + j);
  }

  f32x4 m4 = __builtin_nontemporal_load(reinterpret_cast<const f32x4*>(mu) + f);
  f32x4 r4 = __builtin_nontemporal_load(reinterpret_cast<const f32x4*>(rho) + f);

  float w[4];
  float kl = 0.0f;
#pragma unroll
  for (int d = 0; d < 4; ++d) {
    u32 e = 4u * (u32)f + (u32)d;
    float sp  = softplusf(r4[d]);
    float eps = normal_from_bits(rbits(kw0, kw1, e));
    w[d] = fmaf(sp, eps, m4[d]);
    kl += kl_term(m4[d], sp);
  }

  float y[16];
#pragma unroll
  for (int b = 0; b < 16; ++b) y[b] = 0.0f;
#pragma unroll
  for (int d = 0; d < 4; ++d)
#pragma unroll
    for (int b = 0; b < 16; ++b)
      y[b] = fmaf(__half2float(xg[d].h[b]), w[d], y[b]);

  float m = 0.0f;
#pragma unroll
  for (int b = 0; b < 16; ++b) m += y[b];
  m *= 0.0625f;
  float v = 0.0f;
#pragma unroll
  for (int b = 0; b < 16; ++b) { float dd = y[b] - m; v = fmaf(dd, dd, v); }
  v *= 0.0625f;
  float sc = rsqrtf(v + 1e-5f) * gg[f];
  float bi = bbp[f];

  H16 o;
#pragma unroll
  for (int b = 0; b < 16; ++b) {
    float u = bits_to_u01(rbits(kd0, kd1, (u32)b * (u32)nf + (u32)f));
    float h = fmaxf(fmaf(y[b] - m, sc, bi), 0.0f);
    o.h[b] = __float2half_rn((u < 0.9f) ? h * (1.0f / 0.9f) : 0.0f);
  }
  u32* op = hu_out + (size_t)f * 8;
#pragma unroll
  for (int j = 0; j < 8; ++j) astore(op + j, o.w[j]);
  return kl;
}

// ---------------------------------------------------------------------------
// Stage 5: h4 -> f32 out [16, 524288, 3] (NT stores)
// ---------------------------------------------------------------------------
__device__ __forceinline__ float final_body(
    int f, u32* hu_in, const int* __restrict__ ii,
    const float* __restrict__ mu, const float* __restrict__ rho,
    float* __restrict__ out, u32 kw0, u32 kw1)
{
  const int nf = 524288;
  i32x4 iv = __builtin_nontemporal_load(reinterpret_cast<const i32x4*>(ii) + f);

  H16 xg[4];
#pragma unroll
  for (int d = 0; d < 4; ++d) {
    u32* xp = hu_in + (size_t)iv[d] * 8;
#pragma unroll
    for (int j = 0; j < 8; ++j) xg[d].w[j] = aload1st(xp + j);
  }

  const f32x4* mp = reinterpret_cast<const f32x4*>(mu) + (size_t)f * 3;
  const f32x4* rp = reinterpret_cast<const f32x4*>(rho) + (size_t)f * 3;
  float w[4][3];
  float kl = 0.0f;
#pragma unroll
  for (int h = 0; h < 3; ++h) {
    f32x4 m4 = __builtin_nontemporal_load(mp + h);
    f32x4 r4 = __builtin_nontemporal_load(rp + h);
#pragma unroll
    for (int k = 0; k < 4; ++k) {
      int t = 4 * h + k;                 // flat weight index 0..11 = 3*d+o
      u32 j = 12u * (u32)f + (u32)t;
      float sp  = softplusf(r4[k]);
      float eps = normal_from_bits(rbits(kw0, kw1, j));
      w[t / 3][t % 3] = fmaf(sp, eps, m4[k]);
      kl += kl_term(m4[k], sp);
    }
  }

#pragma unroll
  for (int q = 0; q < 4; ++q) {
    float acc[4][3];
#pragma unroll
    for (int k = 0; k < 4; ++k)
#pragma unroll
      for (int o = 0; o < 3; ++o) acc[k][o] = 0.0f;

#pragma unroll
    for (int d = 0; d < 4; ++d)
#pragma unroll
      for (int k = 0; k < 4; ++k) {
        float xv = __half2float(xg[d].h[4 * q + k]);
#pragma unroll
        for (int o = 0; o < 3; ++o)
          acc[k][o] = fmaf(xv, w[d][o], acc[k][o]);
      }

#pragma unroll
    for (int k = 0; k < 4; ++k) {
      size_t base = ((size_t)(4 * q + k) * nf + (size_t)f) * 3;
      __builtin_nontemporal_store(acc[k][0], out + base + 0);
      __builtin_nontemporal_store(acc[k][1], out + base + 1);
      __builtin_nontemporal_store(acc[k][2], out + base + 2);
    }
  }
  return kl;
}

// ---------------------------------------------------------------------------
// Single-dispatch fused pipeline. 1024 blocks x 256 @ launch_bounds(256,4):
// documented co-residency max (k=4 blocks/CU x 256 CU).
// ---------------------------------------------------------------------------
__global__ __launch_bounds__(256, 4) void fused_all(Params p) {
  const int tid = threadIdx.x;
  const int gid = blockIdx.x * BS + tid;

  float kl = 0.0f;

  if (gid < 2048)
    kl += first_body(gid, p.x0, p.ii1, p.mu1, p.rho1, p.g1, p.b1, p.hu1,
                     p.K[0][0], p.K[0][1], p.K[1][0], p.K[1][1]);
  grid_barrier(p.bar, 1u);

  if (gid < 8192)
    kl += mid_body(gid, 8192, p.hu1, p.ii2, p.mu2, p.rho2, p.g2, p.b2, p.hu2,
                   p.K[2][0], p.K[2][1], p.K[3][0], p.K[3][1]);
  grid_barrier(p.bar, 2u);

  if (gid < 32768)
    kl += mid_body(gid, 32768, p.hu2, p.ii3, p.mu3, p.rho3, p.g3, p.b3, p.hu3,
                   p.K[4][0], p.K[4][1], p.K[5][0], p.K[5][1]);
  grid_barrier(p.bar, 3u);

  if (gid < 131072)
    kl += mid_body(gid, 131072, p.hu3, p.ii4, p.mu4, p.rho4, p.g4, p.b4, p.hu4,
                   p.K[6][0], p.K[6][1], p.K[7][0], p.K[7][1]);
  grid_barrier(p.bar, 4u);

  // stage 5: 524288 nodes = exactly 2 per thread
  kl += final_body(gid,      p.hu4, p.ii5, p.mu5, p.rho5, p.out, p.K[8][0], p.K[8][1]);
  kl += final_body(gid + GT, p.hu4, p.ii5, p.mu5, p.rho5, p.out, p.K[8][0], p.K[8][1]);

  // KL finish: block reduce -> fixed-point u64 atomicAdd (order-independent,
  // deterministic) + done-counter; last block writes the output slot.
  __shared__ float sm[256];
  sm[tid] = kl;
  __syncthreads();
  for (int off = 128; off > 0; off >>= 1) {
    if (tid < off) sm[tid] += sm[tid + off];
    __syncthreads();
  }
  if (tid == 0) {
    u64 fx = (u64)(long long)llrintf(sm[0] * 1048576.0f);   // scale 2^20
    armw_add64((u64*)(p.bar + 3072), fx);
    asm volatile("s_waitcnt vmcnt(0)" ::: "memory");         // add before count
    u32 done = armw_add(p.bar + 3104, 1u);
    if (done == GRID_BLOCKS - 1) {
      u64 tot = armw_add64((u64*)(p.bar + 3072), 0ull);
      p.out[(size_t)16 * 524288 * 3] =
          (float)((double)(long long)tot * (1.0 / 1048576.0));
    }
  }
}

// ---------------------------------------------------------------------------
extern "C" void kernel_launch(void* const* d_in, const int* in_sizes, int n_in,
                              void* d_out, int out_size, void* d_ws, size_t ws_size,
                              hipStream_t stream) {
  Params p;
  p.x0   = (const float*)d_in[0];
  p.ii1  = (const int*)d_in[2];
  p.mu1  = (const float*)d_in[3];
  p.rho1 = (const float*)d_in[4];
  p.g1   = (const float*)d_in[5];
  p.b1   = (const float*)d_in[6];
  p.ii2  = (const int*)d_in[8];
  p.mu2  = (const float*)d_in[9];
  p.rho2 = (const float*)d_in[10];
  p.g2   = (const float*)d_in[11];
  p.b2   = (const float*)d_in[12];
  p.ii3  = (const int*)d_in[14];
  p.mu3  = (const float*)d_in[15];
  p.rho3 = (const float*)d_in[16];
  p.g3   = (const float*)d_in[17];
  p.b3   = (const float*)d_in[18];
  p.ii4  = (const int*)d_in[20];
  p.mu4  = (const float*)d_in[21];
  p.rho4 = (const float*)d_in[22];
  p.g4   = (const float*)d_in[23];
  p.b4   = (const float*)d_in[24];
  p.ii5  = (const int*)d_in[26];
  p.mu5  = (const float*)d_in[27];
  p.rho5 = (const float*)d_in[28];

  u32* wsu = (u32*)d_ws;
  p.out = (float*)d_out;
  p.bar = wsu;                             // u32[4096]: barrier + KL state
  p.hu1 = wsu + 4096;                      // 2048 *8 u32
  p.hu2 = p.hu1 + 2048  * 8;               // 8192 *8
  p.hu3 = p.hu2 + 8192  * 8;               // 32768*8
  p.hu4 = p.hu3 + 32768 * 8;               // 131072*8

  for (u32 i = 0; i < 10; ++i) {
    U2 r = tf2x32(0u, 42u, 0u, i);
    p.K[i][0] = r.a; p.K[i][1] = r.b;
  }

  // zero barrier + KL state every call (graph-capturable async memset)
  hipMemsetAsync(d_ws, 0, 16384, stream);

  fused_all<<<dim3(GRID_BLOCKS), dim3(BS), 0, stream>>>(p);
}

// Round 14
// 102.741 us; speedup vs baseline: 1.8052x; 1.7439x over previous
//
#include <hip/hip_runtime.h>
#include <hip/hip_fp16.h>
#include <stdint.h>

typedef uint32_t u32;
typedef unsigned long long u64;
typedef float    f32x4 __attribute__((ext_vector_type(4)));
typedef int      i32x4 __attribute__((ext_vector_type(4)));
typedef uint32_t u32x4 __attribute__((ext_vector_type(4)));

#define GRID_BLOCKS 1024
#define BS 256
#define GT (GRID_BLOCKS * BS)   // 262144 threads
#define SUBW 64                 // blocks per sub-counter (1024/16)

// ---- agent-scope atomic helpers -------------------------------------------
// RMWs execute at the coherence point (always fresh) -> all cross-XCD polling
// is RMW (r12/r13). Agent atomic STOREs write through the non-coherent L2 ->
// used for producer h-stores. Consumer loads are PLAIN CACHED vector loads:
// dispatch-start agent-acquire invalidated L2, so first touch misses to L3,
// which holds the written-through data. (This is the same mechanism that
// makes ordinary split-kernel pipelines correct on MI355X.)
__device__ __forceinline__ void astore(u32* p, u32 v) {
  __hip_atomic_store(p, v, __ATOMIC_RELAXED, __HIP_MEMORY_SCOPE_AGENT);
}
__device__ __forceinline__ void astore64(u64* p, u64 v) {
  __hip_atomic_store(p, v, __ATOMIC_RELAXED, __HIP_MEMORY_SCOPE_AGENT);
}
__device__ __forceinline__ u32 armw_add(u32* p, u32 v) {
  return __hip_atomic_fetch_add(p, v, __ATOMIC_RELAXED, __HIP_MEMORY_SCOPE_AGENT);
}
__device__ __forceinline__ u64 armw_add64(u64* p, u64 v) {
  return __hip_atomic_fetch_add(p, v, __ATOMIC_RELAXED, __HIP_MEMORY_SCOPE_AGENT);
}

// ---------------------------------------------------------------------------
// threefry2x32 (JAX): bit-exact.
// ---------------------------------------------------------------------------
struct U2 { u32 a, b; };

__host__ __device__ inline U2 tf2x32(u32 k0, u32 k1, u32 x0, u32 x1) {
  u32 k2 = k0 ^ k1 ^ 0x1BD11BDAu;
#define TFR(r) { x0 += x1; x1 = (x1 << (r)) | (x1 >> (32 - (r))); x1 ^= x0; }
  x0 += k0; x1 += k1;
  TFR(13) TFR(15) TFR(26) TFR(6)  x0 += k1; x1 += k2 + 1u;
  TFR(17) TFR(29) TFR(16) TFR(24) x0 += k2; x1 += k0 + 2u;
  TFR(13) TFR(15) TFR(26) TFR(6)  x0 += k0; x1 += k1 + 3u;
  TFR(17) TFR(29) TFR(16) TFR(24) x0 += k1; x1 += k2 + 4u;
  TFR(13) TFR(15) TFR(26) TFR(6)  x0 += k2; x1 += k0 + 5u;
#undef TFR
  return {x0, x1};
}

__device__ __forceinline__ u32 rbits(u32 k0, u32 k1, u32 j) {
  U2 r = tf2x32(k0, k1, 0u, j);
  return r.a ^ r.b;
}

__device__ __forceinline__ float bits_to_u01(u32 bits) {
  return __uint_as_float(0x3F800000u | (bits >> 9)) - 1.0f;
}

__device__ __forceinline__ float bits_to_upm1(u32 bits) {
  const float LO = -0.99999994f;
  float f = bits_to_u01(bits);
  return fmaxf(LO, f * 2.0f + LO);
}

__device__ __forceinline__ float erfinv32(float x) {
  float w = -__logf((1.0f - x) * (1.0f + x));
  float p;
  if (w < 5.0f) {
    w -= 2.5f;
    p = 2.81022636e-08f;
    p = fmaf(p, w, 3.43273939e-07f);
    p = fmaf(p, w, -3.5233877e-06f);
    p = fmaf(p, w, -4.39150654e-06f);
    p = fmaf(p, w, 0.00021858087f);
    p = fmaf(p, w, -0.00125372503f);
    p = fmaf(p, w, -0.00417768164f);
    p = fmaf(p, w, 0.246640727f);
    p = fmaf(p, w, 1.50140941f);
  } else {
    w = sqrtf(w) - 3.0f;
    p = -0.000200214257f;
    p = fmaf(p, w, 0.000100950558f);
    p = fmaf(p, w, 0.00134934322f);
    p = fmaf(p, w, -0.00367342844f);
    p = fmaf(p, w, 0.00573950773f);
    p = fmaf(p, w, -0.0076224613f);
    p = fmaf(p, w, 0.00943887047f);
    p = fmaf(p, w, 1.00167406f);
    p = fmaf(p, w, 2.83297682f);
  }
  return p * x;
}

__device__ __forceinline__ float normal_from_bits(u32 bits) {
  return 1.41421356f * erfinv32(bits_to_upm1(bits));
}

__device__ __forceinline__ float softplusf(float x) {
  return fmaxf(x, 0.0f) + __logf(1.0f + __expf(-fabsf(x)));
}

__device__ __forceinline__ float kl_term(float mu, float sp) {
  return fmaf(0.5f, fmaf(sp, sp, mu * mu), -__logf(sp) - 0.5f);
}

union H16 {
  u32x4 v[2];
  u64 q[4];
  __half h[16];
};

// ---------------------------------------------------------------------------
// Grid barrier (r13 design, proven correct). ws layout (u32 idx):
// sub[i]@i*32 (i<16), master@512, mirror[j]@1024+j*32 (j<64),
// klsum(u64)@3072, klcnt@3104. Zeroed per call.
// ---------------------------------------------------------------------------
__device__ __forceinline__ void grid_barrier(u32* bs, u32 gen_next) {
  __syncthreads();
  if (threadIdx.x == 0) {
    asm volatile("s_waitcnt vmcnt(0)" ::: "memory");   // data stores drained
    u32* sub = bs + (blockIdx.x & 15) * 32;
    u32 s = armw_add(sub, 1u);
    if (s == SUBW - 1) {                               // last in sub-group
      astore(sub, 0u);
      asm volatile("s_waitcnt vmcnt(0)" ::: "memory");
      u32 m = armw_add(bs + 512, 1u);
      if (m == 15u) {                                  // last overall
        astore(bs + 512, 0u);
        asm volatile("s_waitcnt vmcnt(0)" ::: "memory");
#pragma unroll
        for (int j = 0; j < 64; ++j) astore(bs + 1024 + j * 32, gen_next);
      }
    }
    u32* mir = bs + 1024 + (blockIdx.x & 63) * 32;
    u32 it = 0;
    while (armw_add(mir, 0u) < gen_next) {             // RMW poll: L3-fresh
      __builtin_amdgcn_s_sleep(16);
      if (++it > 3000000u) break;                      // hang guard
    }
  }
  __syncthreads();
}

// ---------------------------------------------------------------------------
struct Params {
  const float* x0;
  const int *ii1, *ii2, *ii3, *ii4, *ii5;
  const float *mu1, *mu2, *mu3, *mu4, *mu5;
  const float *rho1, *rho2, *rho3, *rho4, *rho5;
  const float *g1, *g2, *g3, *g4;
  const float *b1, *b2, *b3, *b4;
  u32 *hu1, *hu2, *hu3, *hu4;   // f16 intermediates viewed as u32 words
  float* out;
  u32* bar;        // barrier + KL state (zeroed per call)
  u32 K[10][2];
};

// ---------------------------------------------------------------------------
// Stage 1: x0 batch-major f32 [16,512] -> h1 [2048 nodes x 16]
// h stores: u64 agent atomics (write-through past L2).
// ---------------------------------------------------------------------------
__device__ __forceinline__ float first_body(
    int f, const float* __restrict__ xin,
    const int* __restrict__ ii, const float* __restrict__ mu,
    const float* __restrict__ rho, const float* __restrict__ gg,
    const float* __restrict__ bbp, u32* hu_out,
    u32 kw0, u32 kw1, u32 kd0, u32 kd1)
{
  const int nc = 512, nf = 2048;
  i32x4 iv = __builtin_nontemporal_load(reinterpret_cast<const i32x4*>(ii) + f);
  f32x4 m4 = __builtin_nontemporal_load(reinterpret_cast<const f32x4*>(mu) + f);
  f32x4 r4 = __builtin_nontemporal_load(reinterpret_cast<const f32x4*>(rho) + f);

  float w[4];
  float kl = 0.0f;
#pragma unroll
  for (int d = 0; d < 4; ++d) {
    u32 e = 4u * (u32)f + (u32)d;
    float sp  = softplusf(r4[d]);
    float eps = normal_from_bits(rbits(kw0, kw1, e));
    w[d] = fmaf(sp, eps, m4[d]);
    kl += kl_term(m4[d], sp);
  }

  float y[16];
#pragma unroll
  for (int b = 0; b < 16; ++b) {
    float s = 0.0f;
#pragma unroll
    for (int d = 0; d < 4; ++d) s = fmaf(xin[b * nc + iv[d]], w[d], s);
    y[b] = s;
  }

  float m = 0.0f;
#pragma unroll
  for (int b = 0; b < 16; ++b) m += y[b];
  m *= 0.0625f;
  float v = 0.0f;
#pragma unroll
  for (int b = 0; b < 16; ++b) { float dd = y[b] - m; v = fmaf(dd, dd, v); }
  v *= 0.0625f;
  float sc = rsqrtf(v + 1e-5f) * gg[f];
  float bi = bbp[f];

  H16 o;
#pragma unroll
  for (int b = 0; b < 16; ++b) {
    float u = bits_to_u01(rbits(kd0, kd1, (u32)b * (u32)nf + (u32)f));
    float h = fmaxf(fmaf(y[b] - m, sc, bi), 0.0f);
    o.h[b] = __float2half_rn((u < 0.9f) ? h * (1.0f / 0.9f) : 0.0f);
  }
  u64* op = reinterpret_cast<u64*>(hu_out + (size_t)f * 8);
#pragma unroll
  for (int j = 0; j < 4; ++j) astore64(op + j, o.q[j]);
  return kl;
}

// ---------------------------------------------------------------------------
// Stages 2-4: h[nc] -> h[nf].
// Gathers: PLAIN CACHED dwordx4 loads (first touch this dispatch -> L3-fresh).
// ---------------------------------------------------------------------------
__device__ __forceinline__ float mid_body(
    int f, int nf, const u32* hu_in,
    const int* __restrict__ ii, const float* __restrict__ mu,
    const float* __restrict__ rho, const float* __restrict__ gg,
    const float* __restrict__ bbp, u32* hu_out,
    u32 kw0, u32 kw1, u32 kd0, u32 kd1)
{
  i32x4 iv = __builtin_nontemporal_load(reinterpret_cast<const i32x4*>(ii) + f);

  H16 xg[4];
#pragma unroll
  for (int d = 0; d < 4; ++d) {
    const u32x4* xp = reinterpret_cast<const u32x4*>(hu_in) + (size_t)iv[d] * 2;
    xg[d].v[0] = xp[0];
    xg[d].v[1] = xp[1];
  }

  f32x4 m4 = __builtin_nontemporal_load(reinterpret_cast<const f32x4*>(mu) + f);
  f32x4 r4 = __builtin_nontemporal_load(reinterpret_cast<const f32x4*>(rho) + f);

  float w[4];
  float kl = 0.0f;
#pragma unroll
  for (int d = 0; d < 4; ++d) {
    u32 e = 4u * (u32)f + (u32)d;
    float sp  = softplusf(r4[d]);
    float eps = normal_from_bits(rbits(kw0, kw1, e));
    w[d] = fmaf(sp, eps, m4[d]);
    kl += kl_term(m4[d], sp);
  }

  float y[16];
#pragma unroll
  for (int b = 0; b < 16; ++b) y[b] = 0.0f;
#pragma unroll
  for (int d = 0; d < 4; ++d)
#pragma unroll
    for (int b = 0; b < 16; ++b)
      y[b] = fmaf(__half2float(xg[d].h[b]), w[d], y[b]);

  float m = 0.0f;
#pragma unroll
  for (int b = 0; b < 16; ++b) m += y[b];
  m *= 0.0625f;
  float v = 0.0f;
#pragma unroll
  for (int b = 0; b < 16; ++b) { float dd = y[b] - m; v = fmaf(dd, dd, v); }
  v *= 0.0625f;
  float sc = rsqrtf(v + 1e-5f) * gg[f];
  float bi = bbp[f];

  H16 o;
#pragma unroll
  for (int b = 0; b < 16; ++b) {
    float u = bits_to_u01(rbits(kd0, kd1, (u32)b * (u32)nf + (u32)f));
    float h = fmaxf(fmaf(y[b] - m, sc, bi), 0.0f);
    o.h[b] = __float2half_rn((u < 0.9f) ? h * (1.0f / 0.9f) : 0.0f);
  }
  u64* op = reinterpret_cast<u64*>(hu_out + (size_t)f * 8);
#pragma unroll
  for (int j = 0; j < 4; ++j) astore64(op + j, o.q[j]);
  return kl;
}

// ---------------------------------------------------------------------------
// Stage 5: h4 -> f32 out [16, 524288, 3] (NT out stores; cached gathers)
// ---------------------------------------------------------------------------
__device__ __forceinline__ float final_body(
    int f, const u32* hu_in, const int* __restrict__ ii,
    const float* __restrict__ mu, const float* __restrict__ rho,
    float* __restrict__ out, u32 kw0, u32 kw1)
{
  const int nf = 524288;
  i32x4 iv = __builtin_nontemporal_load(reinterpret_cast<const i32x4*>(ii) + f);

  H16 xg[4];
#pragma unroll
  for (int d = 0; d < 4; ++d) {
    const u32x4* xp = reinterpret_cast<const u32x4*>(hu_in) + (size_t)iv[d] * 2;
    xg[d].v[0] = xp[0];
    xg[d].v[1] = xp[1];
  }

  const f32x4* mp = reinterpret_cast<const f32x4*>(mu) + (size_t)f * 3;
  const f32x4* rp = reinterpret_cast<const f32x4*>(rho) + (size_t)f * 3;
  float w[4][3];
  float kl = 0.0f;
#pragma unroll
  for (int h = 0; h < 3; ++h) {
    f32x4 m4 = __builtin_nontemporal_load(mp + h);
    f32x4 r4 = __builtin_nontemporal_load(rp + h);
#pragma unroll
    for (int k = 0; k < 4; ++k) {
      int t = 4 * h + k;                 // flat weight index 0..11 = 3*d+o
      u32 j = 12u * (u32)f + (u32)t;
      float sp  = softplusf(r4[k]);
      float eps = normal_from_bits(rbits(kw0, kw1, j));
      w[t / 3][t % 3] = fmaf(sp, eps, m4[k]);
      kl += kl_term(m4[k], sp);
    }
  }

#pragma unroll
  for (int q = 0; q < 4; ++q) {
    float acc[4][3];
#pragma unroll
    for (int k = 0; k < 4; ++k)
#pragma unroll
      for (int o = 0; o < 3; ++o) acc[k][o] = 0.0f;

#pragma unroll
    for (int d = 0; d < 4; ++d)
#pragma unroll
      for (int k = 0; k < 4; ++k) {
        float xv = __half2float(xg[d].h[4 * q + k]);
#pragma unroll
        for (int o = 0; o < 3; ++o)
          acc[k][o] = fmaf(xv, w[d][o], acc[k][o]);
      }

#pragma unroll
    for (int k = 0; k < 4; ++k) {
      size_t base = ((size_t)(4 * q + k) * nf + (size_t)f) * 3;
      __builtin_nontemporal_store(acc[k][0], out + base + 0);
      __builtin_nontemporal_store(acc[k][1], out + base + 1);
      __builtin_nontemporal_store(acc[k][2], out + base + 2);
    }
  }
  return kl;
}

// ---------------------------------------------------------------------------
// Single-dispatch fused pipeline. 1024 blocks x 256 @ launch_bounds(256,4):
// co-residency max (4 blocks/CU x 256 CU).
// ---------------------------------------------------------------------------
__global__ __launch_bounds__(256, 4) void fused_all(Params p) {
  const int tid = threadIdx.x;
  const int gid = blockIdx.x * BS + tid;

  float kl = 0.0f;

  if (gid < 2048)
    kl += first_body(gid, p.x0, p.ii1, p.mu1, p.rho1, p.g1, p.b1, p.hu1,
                     p.K[0][0], p.K[0][1], p.K[1][0], p.K[1][1]);
  grid_barrier(p.bar, 1u);

  if (gid < 8192)
    kl += mid_body(gid, 8192, p.hu1, p.ii2, p.mu2, p.rho2, p.g2, p.b2, p.hu2,
                   p.K[2][0], p.K[2][1], p.K[3][0], p.K[3][1]);
  grid_barrier(p.bar, 2u);

  if (gid < 32768)
    kl += mid_body(gid, 32768, p.hu2, p.ii3, p.mu3, p.rho3, p.g3, p.b3, p.hu3,
                   p.K[4][0], p.K[4][1], p.K[5][0], p.K[5][1]);
  grid_barrier(p.bar, 3u);

  if (gid < 131072)
    kl += mid_body(gid, 131072, p.hu3, p.ii4, p.mu4, p.rho4, p.g4, p.b4, p.hu4,
                   p.K[6][0], p.K[6][1], p.K[7][0], p.K[7][1]);
  grid_barrier(p.bar, 4u);

  // stage 5: 524288 nodes = exactly 2 per thread
  kl += final_body(gid,      p.hu4, p.ii5, p.mu5, p.rho5, p.out, p.K[8][0], p.K[8][1]);
  kl += final_body(gid + GT, p.hu4, p.ii5, p.mu5, p.rho5, p.out, p.K[8][0], p.K[8][1]);

  // KL finish: block reduce -> fixed-point u64 atomicAdd (order-independent,
  // deterministic) + done-counter; last block writes the output slot.
  __shared__ float sm[256];
  sm[tid] = kl;
  __syncthreads();
  for (int off = 128; off > 0; off >>= 1) {
    if (tid < off) sm[tid] += sm[tid + off];
    __syncthreads();
  }
  if (tid == 0) {
    u64 fx = (u64)(long long)llrintf(sm[0] * 1048576.0f);   // scale 2^20
    armw_add64((u64*)(p.bar + 3072), fx);
    asm volatile("s_waitcnt vmcnt(0)" ::: "memory");         // add before count
    u32 done = armw_add(p.bar + 3104, 1u);
    if (done == GRID_BLOCKS - 1) {
      u64 tot = armw_add64((u64*)(p.bar + 3072), 0ull);
      p.out[(size_t)16 * 524288 * 3] =
          (float)((double)(long long)tot * (1.0 / 1048576.0));
    }
  }
}

// ---------------------------------------------------------------------------
extern "C" void kernel_launch(void* const* d_in, const int* in_sizes, int n_in,
                              void* d_out, int out_size, void* d_ws, size_t ws_size,
                              hipStream_t stream) {
  Params p;
  p.x0   = (const float*)d_in[0];
  p.ii1  = (const int*)d_in[2];
  p.mu1  = (const float*)d_in[3];
  p.rho1 = (const float*)d_in[4];
  p.g1   = (const float*)d_in[5];
  p.b1   = (const float*)d_in[6];
  p.ii2  = (const int*)d_in[8];
  p.mu2  = (const float*)d_in[9];
  p.rho2 = (const float*)d_in[10];
  p.g2   = (const float*)d_in[11];
  p.b2   = (const float*)d_in[12];
  p.ii3  = (const int*)d_in[14];
  p.mu3  = (const float*)d_in[15];
  p.rho3 = (const float*)d_in[16];
  p.g3   = (const float*)d_in[17];
  p.b3   = (const float*)d_in[18];
  p.ii4  = (const int*)d_in[20];
  p.mu4  = (const float*)d_in[21];
  p.rho4 = (const float*)d_in[22];
  p.g4   = (const float*)d_in[23];
  p.b4   = (const float*)d_in[24];
  p.ii5  = (const int*)d_in[26];
  p.mu5  = (const float*)d_in[27];
  p.rho5 = (const float*)d_in[28];

  u32* wsu = (u32*)d_ws;
  p.out = (float*)d_out;
  p.bar = wsu;                             // u32[4096]: barrier + KL state
  p.hu1 = wsu + 4096;                      // 2048 *8 u32
  p.hu2 = p.hu1 + 2048  * 8;               // 8192 *8
  p.hu3 = p.hu2 + 8192  * 8;               // 32768*8
  p.hu4 = p.hu3 + 32768 * 8;               // 131072*8

  for (u32 i = 0; i < 10; ++i) {
    U2 r = tf2x32(0u, 42u, 0u, i);
    p.K[i][0] = r.a; p.K[i][1] = r.b;
  }

  // zero barrier + KL state every call (graph-capturable async memset)
  hipMemsetAsync(d_ws, 0, 16384, stream);

  fused_all<<<dim3(GRID_BLOCKS), dim3(BS), 0, stream>>>(p);
}